// Round 9
// baseline (1790.185 us; speedup 1.0000x reference)
//
#include <hip/hip_runtime.h>
#include <stdint.h>

#define NN 50000   // nodes
#define NE 800000  // edges
#define HD 128     // hidden
#define NL 4       // layers
#define NM 64      // nodes per block (node kernel)
#define EB 64      // edges per block (edge kernel)

typedef __bf16 bf16x8 __attribute__((ext_vector_type(8)));
typedef __bf16 bf16x4 __attribute__((ext_vector_type(4)));
typedef float  f32x4  __attribute__((ext_vector_type(4)));

__device__ __forceinline__ f32x4 mfma16(bf16x8 a, bf16x8 b, f32x4 c) {
  return __builtin_amdgcn_mfma_f32_16x16x32_bf16(a, b, c, 0, 0, 0);
}

template<int MT, int NT>
__device__ __forceinline__ void zero_acc(f32x4 (&acc)[MT][NT]) {
#pragma unroll
  for (int i = 0; i < MT; ++i)
#pragma unroll
    for (int j = 0; j < NT; ++j) acc[i][j] = f32x4{0.f, 0.f, 0.f, 0.f};
}

// ---------------- generic MT/NT gemm chunk ----------------------------------
template<int MT, int NT, int KS>
__device__ __forceinline__ void gemm_chunk(const __bf16* A, int sa,
    const __bf16* __restrict__ Bt, int Krow, int k0,
    int m_off, int n_off, int lane, f32x4 (&acc)[MT][NT])
{
  const int arow = lane & 15;
  const int quad = lane >> 4;
  bf16x8 b[KS][NT];
#pragma unroll
  for (int ks = 0; ks < KS; ++ks)
#pragma unroll
    for (int nt = 0; nt < NT; ++nt)
      b[ks][nt] = *reinterpret_cast<const bf16x8*>(
          Bt + (size_t)(n_off + nt * 16 + arow) * Krow + k0 + ks * 32 + quad * 8);
#pragma unroll
  for (int ks = 0; ks < KS; ++ks) {
    const int k = k0 + ks * 32 + quad * 8;
    bf16x8 a[MT];
#pragma unroll
    for (int mt = 0; mt < MT; ++mt)
      a[mt] = *reinterpret_cast<const bf16x8*>(A + (m_off + mt * 16 + arow) * sa + k);
#pragma unroll
    for (int mt = 0; mt < MT; ++mt)
#pragma unroll
      for (int nt = 0; nt < NT; ++nt)
        acc[mt][nt] = mfma16(a[mt], b[ks][nt], acc[mt][nt]);
  }
}

// C/D layout (m89-verified): col = lane&15, row = (lane>>4)*4 + reg
template<int MT, int NT, bool RELU>
__device__ __forceinline__ void store_tile(__bf16* O, int so,
    const float* __restrict__ bias, int m_off, int n_off, int lane,
    f32x4 (&acc)[MT][NT])
{
  const int quad = lane >> 4;
  const int cl = lane & 15;
#pragma unroll
  for (int nt = 0; nt < NT; ++nt) {
    const int col = n_off + nt * 16 + cl;
    const float bv = bias[col];
#pragma unroll
    for (int mt = 0; mt < MT; ++mt)
#pragma unroll
      for (int r = 0; r < 4; ++r) {
        const int row = m_off + mt * 16 + quad * 4 + r;
        float v = acc[mt][nt][r] + bv;
        if (RELU) v = fmaxf(v, 0.f);
        O[row * so + col] = (__bf16)v;
      }
  }
}

// ---- prep: W[l][K0][128] fp32 -> Wt[l][128][Kp] bf16 (transposed, zero-pad K)
__global__ void prep_w(const float* __restrict__ W, __bf16* __restrict__ Wt,
                       int K0, int Kp) {
  int idx = blockIdx.x * 256 + threadIdx.x;
  int total = NL * HD * Kp;
  if (idx >= total) return;
  int l = idx / (HD * Kp);
  int rem = idx - l * HD * Kp;
  int n = rem / Kp;
  int k = rem - n * Kp;
  float v = (k < K0) ? W[((size_t)l * K0 + k) * HD + n] : 0.f;
  Wt[idx] = (__bf16)v;
}

// ---- prep P/Q weights: fold rel_mom rows (260:263) into h_col/h_row blocks.
__global__ void prep_pqw(const float* __restrict__ We1,
                         __bf16* __restrict__ Wtopt, __bf16* __restrict__ Wbott) {
  int idx = blockIdx.x * 256 + threadIdx.x;
  if (idx >= NL * HD * HD) return;
  int l = idx / (HD * HD);
  int rem = idx - l * HD * HD;
  int n = rem >> 7;
  int k = rem & 127;
  const float* W = We1 + (size_t)l * 263 * HD;
  float extra = (k >= 3 && k < 6) ? W[(260 + k - 3) * HD + n] : 0.f;
  Wtopt[idx] = (__bf16)(W[k * HD + n] + extra);
  Wbott[idx] = (__bf16)(W[(128 + k) * HD + n] - extra);
}

// ---- h0 = x @ W_in + b_in
__global__ void h0_kernel(const float* __restrict__ x, const float* __restrict__ W,
                          const float* __restrict__ b, float* __restrict__ H32,
                          __bf16* __restrict__ HB) {
  int idx = blockIdx.x * 256 + threadIdx.x;
  if (idx >= NN * HD) return;
  int node = idx >> 7, j = idx & 127;
  const float* xr = x + node * 16;
  float s = b[j];
#pragma unroll
  for (int k = 0; k < 16; ++k) s += xr[k] * W[k * HD + j];
  H32[idx] = s;
  HB[idx] = (__bf16)s;
}

// ---- CSR build (counting sort of edges by col), emitting sorted ROW/COL
__global__ void hist_kernel(const int* __restrict__ ei, int* __restrict__ cnt) {
  int e = blockIdx.x * 256 + threadIdx.x;
  if (e < NE) atomicAdd(&cnt[ei[NE + e]], 1);
}

__global__ void scan_kernel(const int* __restrict__ cnt, int* __restrict__ cur) {
  __shared__ int wsum[16];
  __shared__ int carry;
  int t = threadIdx.x;           // 1024 threads
  int lane = t & 63, wid = t >> 6;
  if (t == 0) carry = 0;
  __syncthreads();
  for (int base = 0; base < NN; base += 1024) {
    int v = (base + t < NN) ? cnt[base + t] : 0;
    int incl = v;
#pragma unroll
    for (int off = 1; off < 64; off <<= 1) {
      int u = __shfl_up(incl, off, 64);
      if (lane >= off) incl += u;
    }
    if (lane == 63) wsum[wid] = incl;
    __syncthreads();
    int woff = 0;
    for (int k = 0; k < wid; ++k) woff += wsum[k];
    int c = carry;
    if (base + t < NN) cur[base + t] = c + woff + incl - v;
    __syncthreads();
    if (t == 1023) carry = c + woff + incl;
    __syncthreads();
  }
}

__global__ void scatter_kernel(const int* __restrict__ ei, int* __restrict__ cur,
                               int* __restrict__ ROWS, int* __restrict__ COLS) {
  int e = blockIdx.x * 256 + threadIdx.x;
  if (e < NE) {
    int r = ei[e], c = ei[NE + e];
    int p = atomicAdd(&cur[c], 1);
    ROWS[p] = r;
    COLS[p] = c;
  }
}

// ---- per-edge dist only (rel_pos part of ea is folded into P/Q)
__global__ void dist_kernel(const float* __restrict__ pos,
                            const int* __restrict__ ROWS, const int* __restrict__ COLS,
                            __bf16* __restrict__ DSTb) {
  int p = blockIdx.x * 256 + threadIdx.x;
  if (p >= NE) return;
  int r = ROWS[p], c = COLS[p];
  float dx = pos[c * 3 + 0] - pos[r * 3 + 0];
  float dy = pos[c * 3 + 1] - pos[r * 3 + 1];
  float dz = pos[c * 3 + 2] - pos[r * 3 + 2];
  DSTb[p] = (__bf16)sqrtf(dx * dx + dy * dy + dz * dz);
}

// ---- P/Q kernel v2: P = h@Wtop^T + pos@W4xyz + be1 ; Q = h@Wbot^T - pos@W4xyz
__global__ __launch_bounds__(256, 4) void pq_kernel(
    const __bf16* __restrict__ HB, const float* __restrict__ pos,
    const __bf16* __restrict__ Wtopt, const __bf16* __restrict__ Wbott,
    const float* __restrict__ W4xyz,   // We1_l rows 256..258 : [3][128]
    const float* __restrict__ be1,
    __bf16* __restrict__ PB, __bf16* __restrict__ QB)
{
  const int task = blockIdx.x * 4 + (threadIdx.x >> 6);
  const int lane = threadIdx.x & 63;
  const int g = task & 1;                 // 0 -> P, 1 -> Q
  const int base = (task >> 1) * 32;
  if (base >= NN) return;
  const int arow = lane & 15, quad = lane >> 4, cl = lane & 15;

  const __bf16* Wt = g ? Wbott : Wtopt;
  __bf16* O = g ? QB : PB;
  f32x4 acc[2][8];
  zero_acc(acc);
#pragma unroll
  for (int ks = 0; ks < 4; ++ks) {
    const int k = ks * 32 + quad * 8;
    bf16x8 b[8];
#pragma unroll
    for (int nt = 0; nt < 8; ++nt)
      b[nt] = *reinterpret_cast<const bf16x8*>(Wt + (size_t)(nt * 16 + arow) * HD + k);
    bf16x8 a[2];
#pragma unroll
    for (int mt = 0; mt < 2; ++mt) {
      int row = base + mt * 16 + arow;
      if (row >= NN) row = NN - 1;         // clamp (stores guarded)
      a[mt] = *reinterpret_cast<const bf16x8*>(HB + (size_t)row * HD + k);
    }
#pragma unroll
    for (int mt = 0; mt < 2; ++mt)
#pragma unroll
      for (int nt = 0; nt < 8; ++nt)
        acc[mt][nt] = mfma16(a[mt], b[nt], acc[mt][nt]);
  }
  float px[2][4], py[2][4], pz[2][4];
#pragma unroll
  for (int mt = 0; mt < 2; ++mt)
#pragma unroll
    for (int r = 0; r < 4; ++r) {
      int row = base + mt * 16 + quad * 4 + r;
      if (row >= NN) row = NN - 1;
      px[mt][r] = pos[row * 3 + 0];
      py[mt][r] = pos[row * 3 + 1];
      pz[mt][r] = pos[row * 3 + 2];
    }
#pragma unroll
  for (int nt = 0; nt < 8; ++nt) {
    const int col = nt * 16 + cl;
    const float w0 = W4xyz[col], w1 = W4xyz[HD + col], w2 = W4xyz[2 * HD + col];
    const float bb = g ? 0.f : be1[col];
#pragma unroll
    for (int mt = 0; mt < 2; ++mt)
#pragma unroll
      for (int r = 0; r < 4; ++r) {
        const int row = base + mt * 16 + quad * 4 + r;
        if (row < NN) {
          float dot = px[mt][r] * w0 + py[mt][r] * w1 + pz[mt][r] * w2;
          float v = acc[mt][nt][r] + (g ? -dot : dot) + bb;
          O[(size_t)row * HD + col] = (__bf16)v;
        }
      }
  }
}

// ---- edge kernel v4b: r7 structure, 8 blocks/CU target.
//  combine: m1 = relu(P[col] + Q[row] + dist*w4d)       (4 ops/elem)
//  GEMM2:   m2 = relu(m1 @ We2 + be2)                   (MFMA, reg acc)
//  GEMM3:   m3 = m2 @ We3 + be3
//  reduce:  r3-proven block-level all-atomic segmented reduce (low WRITE)
// r7 measured VGPR=44, LDS=19456B -> both fit 8 blocks/CU (156KB LDS, 64 VGPR cap)
__global__ __launch_bounds__(256, 8) void edge_kernel(
    const __bf16* __restrict__ PB, const __bf16* __restrict__ QB,
    const __bf16* __restrict__ DSTb,
    const int* __restrict__ ROWS, const int* __restrict__ COLS,
    const float* __restrict__ w4d,      // We1_l row 259 (dist), 128 f32
    const __bf16* __restrict__ We2t, const __bf16* __restrict__ We3t,
    const float* __restrict__ be2, const float* __restrict__ be3,
    float* __restrict__ AGG)
{
  __shared__ __bf16 S[EB * 136];
  __shared__ float w4ds[HD], be2s[HD], be3s[HD];
  __shared__ int colS[EB];
  const int t = threadIdx.x;
  const int base = blockIdx.x * EB;

  if (t < HD) { w4ds[t] = w4d[t]; be2s[t] = be2[t]; be3s[t] = be3[t]; }
  if (t < EB) colS[t] = COLS[base + t];
  __syncthreads();                              // B0: w4ds ready

  // ---- gather + combine -> m1 tile. thread t: row i = t>>2, 4 chunks of 8.
  {
    const int i = t >> 2, cg = t & 3;
    const int p = base + i;
    const int c = colS[i];
    const int r = ROWS[p];
    const float dist = (float)DSTb[p];
    const __bf16* Prow = PB + (size_t)c * HD;
    const __bf16* Qrow = QB + (size_t)r * HD;
#pragma unroll
    for (int u = 0; u < 4; ++u) {
      const int ch = cg * 4 + u;
      bf16x8 pv = *reinterpret_cast<const bf16x8*>(Prow + ch * 8);
      bf16x8 qv = *reinterpret_cast<const bf16x8*>(Qrow + ch * 8);
      bf16x8 o;
#pragma unroll
      for (int j = 0; j < 8; ++j) {
        const int col = ch * 8 + j;
        float f = (float)pv[j] + (float)qv[j] + dist * w4ds[col];
        o[j] = (__bf16)fmaxf(f, 0.f);
      }
      *reinterpret_cast<bf16x8*>(S + i * 136 + ch * 8) = o;
    }
  }
  __syncthreads();                              // B1: m1 complete

  const int w = t >> 6, lane = t & 63;
  const int m_off = (w >> 1) * 32, n_off = (w & 1) * 64;   // wave: 32x64 tile
  const int arow = lane & 15, quad = lane >> 4, cl = lane & 15;

  f32x4 acc[2][4];
#pragma unroll
  for (int g = 0; g < 2; ++g) {
    const __bf16* Wt = g ? We3t : We2t;
    const float* bs = g ? be3s : be2s;
    zero_acc(acc);
#pragma unroll
    for (int half = 0; half < 2; ++half) {      // K=128 as 2 batches of 64
      bf16x8 b[2][4];
#pragma unroll
      for (int ks = 0; ks < 2; ++ks)
#pragma unroll
        for (int nt = 0; nt < 4; ++nt)
          b[ks][nt] = *reinterpret_cast<const bf16x8*>(
              Wt + (size_t)(n_off + nt * 16 + arow) * HD + half * 64 + ks * 32 + quad * 8);
#pragma unroll
      for (int ks = 0; ks < 2; ++ks) {
        const int k = half * 64 + ks * 32 + quad * 8;
        bf16x8 a[2];
#pragma unroll
        for (int mt = 0; mt < 2; ++mt)
          a[mt] = *reinterpret_cast<const bf16x8*>(S + (m_off + mt * 16 + arow) * 136 + k);
#pragma unroll
        for (int mt = 0; mt < 2; ++mt)
#pragma unroll
          for (int nt = 0; nt < 4; ++nt)
            acc[mt][nt] = mfma16(a[mt], b[ks][nt], acc[mt][nt]);
      }
    }
    __syncthreads();                            // all waves done reading S
#pragma unroll
    for (int nt = 0; nt < 4; ++nt) {
      const int col = n_off + nt * 16 + cl;
      const float bv = bs[col];
#pragma unroll
      for (int mt = 0; mt < 2; ++mt)
#pragma unroll
        for (int r = 0; r < 4; ++r) {
          const int row = m_off + mt * 16 + quad * 4 + r;
          float v = acc[mt][nt][r] + bv;
          if (!g) v = fmaxf(v, 0.f);
          S[row * 136 + col] = (__bf16)v;
        }
    }
    __syncthreads();                            // m(g+2) visible to all
  }

  // ---- block-level segmented reduce (r3-proven): col j, 32-row halves.
  {
    const int j = t & 127, hh = t >> 7;
    const int i0 = hh * 32, i1 = i0 + 32;
    float s = 0.f;
    for (int i = i0; i < i1; ++i) {
      s += (float)S[i * 136 + j];
      const int c = colS[i];
      if (i == i1 - 1 || colS[i + 1] != c) {
        atomicAdd(&AGG[(size_t)c * HD + j], s);
        s = 0.f;
      }
    }
  }
}

// ---- node MLP + residual + LayerNorm. 64 nodes/block, MT=2/NT=4 waves,
// LDS ~36.5 KB -> 4 blocks/CU (r7 ran 128/block at 2 blocks/CU).
__global__ __launch_bounds__(256, 4) void node_kernel(
    const __bf16* __restrict__ HBin, const float* __restrict__ AGG,
    const __bf16* __restrict__ Wn1t, const __bf16* __restrict__ Wn2t,
    const __bf16* __restrict__ Wn3t,
    const float* __restrict__ bn1, const float* __restrict__ bn2,
    const float* __restrict__ bn3,
    const float* __restrict__ lng, const float* __restrict__ lnb,
    float* __restrict__ H32, __bf16* __restrict__ HBout,
    float* __restrict__ dout)
{
  __shared__ float SB[NM * 136];                 // 34.8 KB union
  __shared__ float ps[NM][2], psq[NM][2];
  __shared__ float mean_s[NM], rstd_s[NM];
  __bf16* B16 = reinterpret_cast<__bf16*>(SB);
  const int t = threadIdx.x;
  const int base = blockIdx.x * NM;

  {
    const int i0 = t >> 4, s = t & 15;
#pragma unroll
    for (int g = 0; g < NM / 16; ++g) {
      const int i = g * 16 + i0;
      const int node = base + i;
      uint4 v = make_uint4(0, 0, 0, 0);
      if (node < NN) v = *(reinterpret_cast<const uint4*>(HBin + (size_t)node * HD) + s);
      *reinterpret_cast<uint4*>(&B16[i * 264 + s * 8]) = v;
    }
  }
  for (int idx = t; idx < NM * 32; idx += 256) {
    const int i = idx >> 5, c4 = idx & 31;
    const int node = base + i;
    float4 v = make_float4(0.f, 0.f, 0.f, 0.f);
    if (node < NN) v = *reinterpret_cast<const float4*>(AGG + (size_t)node * HD + c4 * 4);
    __bf16* d = &B16[i * 264 + HD + c4 * 4];
    d[0] = (__bf16)v.x; d[1] = (__bf16)v.y; d[2] = (__bf16)v.z; d[3] = (__bf16)v.w;
  }
  __syncthreads();

  const int w = t >> 6, lane = t & 63;
  const int m_off = (w >> 1) * 32, n_off = (w & 1) * 64;   // wave: 32x64 tile
  f32x4 acc[2][4];
  __bf16* reg0 = B16;                            // stride 136, [0, 17408)
  __bf16* reg1 = B16 + NM * 136;                 // stride 136, [17408, 34816)

  zero_acc(acc);
  gemm_chunk<2, 4, 4>(B16, 264, Wn1t, 256, 0,   m_off, n_off, lane, acc);
  gemm_chunk<2, 4, 4>(B16, 264, Wn1t, 256, 128, m_off, n_off, lane, acc);
  __syncthreads();                               // A reads done
  store_tile<2, 4, true>(reg0, 136, bn1, m_off, n_off, lane, acc);
  __syncthreads();
  zero_acc(acc);
  gemm_chunk<2, 4, 4>(reg0, 136, Wn2t, 128, 0, m_off, n_off, lane, acc);
  store_tile<2, 4, true>(reg1, 136, bn2, m_off, n_off, lane, acc);   // disjoint
  __syncthreads();
  zero_acc(acc);
  gemm_chunk<2, 4, 4>(reg1, 136, Wn3t, 128, 0, m_off, n_off, lane, acc);
  __syncthreads();                               // reg1 reads done

  {
    const int quad = lane >> 4, cl = lane & 15;
#pragma unroll
    for (int nt = 0; nt < 4; ++nt) {
      const int col = n_off + nt * 16 + cl;
      const float bv = bn3[col];
#pragma unroll
      for (int mt = 0; mt < 2; ++mt)
#pragma unroll
        for (int r = 0; r < 4; ++r) {
          const int row = m_off + mt * 16 + quad * 4 + r;
          const int node = base + row;
          float hv = (node < NN) ? H32[(size_t)node * HD + col] : 0.f;
          SB[row * 136 + col] = hv + acc[mt][nt][r] + bv;
        }
    }
  }
  __syncthreads();
  if (t < 128) {
    const int r = t >> 1, hh = t & 1;
    float s = 0.f, sq = 0.f;
    for (int j = hh * 64; j < hh * 64 + 64; ++j) {
      float v = SB[r * 136 + j];
      s += v; sq += v * v;
    }
    ps[r][hh] = s; psq[r][hh] = sq;
  }
  __syncthreads();
  if (t < NM) {
    float s = ps[t][0] + ps[t][1];
    float sq = psq[t][0] + psq[t][1];
    float mean = s * (1.f / HD);
    float var = sq * (1.f / HD) - mean * mean;
    mean_s[t] = mean;
    rstd_s[t] = rsqrtf(var + 1e-5f);
  }
  __syncthreads();
  for (int idx = t; idx < NM * HD; idx += 256) {
    const int r = idx >> 7, j = idx & 127;
    const int node = base + r;
    if (node < NN) {
      float v = (SB[r * 136 + j] - mean_s[r]) * rstd_s[r] * lng[j] + lnb[j];
      H32[(size_t)node * HD + j] = v;
      HBout[(size_t)node * HD + j] = (__bf16)v;
      if (dout) dout[(size_t)node * HD + j] = v;
    }
  }
}

extern "C" void kernel_launch(void* const* d_in, const int* in_sizes, int n_in,
                              void* d_out, int out_size, void* d_ws, size_t ws_size,
                              hipStream_t stream)
{
  const float* x    = (const float*)d_in[0];
  const float* pos  = (const float*)d_in[1];
  const int*   ei   = (const int*)d_in[2];
  const float* W_in = (const float*)d_in[3];
  const float* b_in = (const float*)d_in[4];
  const float* We1  = (const float*)d_in[5];
  const float* be1  = (const float*)d_in[6];
  const float* We2  = (const float*)d_in[7];
  const float* be2  = (const float*)d_in[8];
  const float* We3  = (const float*)d_in[9];
  const float* be3  = (const float*)d_in[10];
  const float* Wn1  = (const float*)d_in[11];
  const float* bn1  = (const float*)d_in[12];
  const float* Wn2  = (const float*)d_in[13];
  const float* bn2  = (const float*)d_in[14];
  const float* Wn3  = (const float*)d_in[15];
  const float* bn3  = (const float*)d_in[16];
  const float* lng  = (const float*)d_in[17];
  const float* lnb  = (const float*)d_in[18];
  float* out = (float*)d_out;

  char* ws = (char*)d_ws;
  size_t off = 0;
  auto alloc = [&](size_t bytes) -> char* {
    char* p = ws + off;
    off += (bytes + 255) & ~(size_t)255;
    return p;
  };
  __bf16* Wtopt = (__bf16*)alloc((size_t)NL * HD * HD * 2);
  __bf16* Wbott = (__bf16*)alloc((size_t)NL * HD * HD * 2);
  __bf16* We2t = (__bf16*)alloc((size_t)NL * HD * HD * 2);
  __bf16* We3t = (__bf16*)alloc((size_t)NL * HD * HD * 2);
  __bf16* Wn1t = (__bf16*)alloc((size_t)NL * HD * 256 * 2);
  __bf16* Wn2t = (__bf16*)alloc((size_t)NL * HD * HD * 2);
  __bf16* Wn3t = (__bf16*)alloc((size_t)NL * HD * HD * 2);
  __bf16* DSTb = (__bf16*)alloc((size_t)NE * 2);
  float*  H32  = (float*) alloc((size_t)NN * HD * 4);
  __bf16* HB   = (__bf16*)alloc((size_t)NN * HD * 2);
  __bf16* PB   = (__bf16*)alloc((size_t)NN * HD * 2);
  __bf16* QB   = (__bf16*)alloc((size_t)NN * HD * 2);
  float*  AGG  = (float*) alloc((size_t)NN * HD * 4);
  int*    CNT  = (int*)   alloc((size_t)NN * 4);
  int*    CUR  = (int*)   alloc((size_t)NN * 4);
  int*    ROWS = (int*)   alloc((size_t)NE * 4);
  int*    COLS = (int*)   alloc((size_t)NE * 4);

  hipMemsetAsync(CNT, 0, (size_t)NN * 4, stream);
  prep_pqw<<<(NL * HD * HD + 255) / 256, 256, 0, stream>>>(We1, Wtopt, Wbott);
  prep_w<<<(NL * HD * HD + 255) / 256, 256, 0, stream>>>(We2, We2t, 128, 128);
  prep_w<<<(NL * HD * HD + 255) / 256, 256, 0, stream>>>(We3, We3t, 128, 128);
  prep_w<<<(NL * HD * 256 + 255) / 256, 256, 0, stream>>>(Wn1, Wn1t, 256, 256);
  prep_w<<<(NL * HD * HD + 255) / 256, 256, 0, stream>>>(Wn2, Wn2t, 128, 128);
  prep_w<<<(NL * HD * HD + 255) / 256, 256, 0, stream>>>(Wn3, Wn3t, 128, 128);
  h0_kernel<<<(NN * HD + 255) / 256, 256, 0, stream>>>(x, W_in, b_in, H32, HB);
  hist_kernel<<<(NE + 255) / 256, 256, 0, stream>>>(ei, CNT);
  scan_kernel<<<1, 1024, 0, stream>>>(CNT, CUR);
  scatter_kernel<<<(NE + 255) / 256, 256, 0, stream>>>(ei, CUR, ROWS, COLS);
  dist_kernel<<<(NE + 255) / 256, 256, 0, stream>>>(pos, ROWS, COLS, DSTb);

  const int pq_tasks = 2 * ((NN + 31) / 32);
  const int pq_blocks = (pq_tasks + 3) / 4;
  for (int l = 0; l < NL; ++l) {
    const float* We1l = We1 + (size_t)l * 263 * HD;
    pq_kernel<<<pq_blocks, 256, 0, stream>>>(HB, pos,
        Wtopt + (size_t)l * HD * HD, Wbott + (size_t)l * HD * HD,
        We1l + 256 * HD,            // W4xyz rows 256..258
        be1 + l * HD, PB, QB);
    hipMemsetAsync(AGG, 0, (size_t)NN * HD * 4, stream);
    edge_kernel<<<NE / EB, 256, 0, stream>>>(PB, QB, DSTb, ROWS, COLS,
        We1l + 259 * HD,            // w4d (dist row)
        We2t + (size_t)l * HD * HD, We3t + (size_t)l * HD * HD,
        be2 + l * HD, be3 + l * HD, AGG);
    node_kernel<<<(NN + NM - 1) / NM, 256, 0, stream>>>(HB, AGG,
        Wn1t + (size_t)l * HD * 256, Wn2t + (size_t)l * HD * HD,
        Wn3t + (size_t)l * HD * HD,
        bn1 + l * HD, bn2 + l * HD, bn3 + l * HD,
        lng + l * HD, lnb + l * HD,
        H32, HB, (l == NL - 1) ? out : nullptr);
  }
}

// Round 11
// 1505.549 us; speedup vs baseline: 1.1891x; 1.1891x over previous
//
#include <hip/hip_runtime.h>
#include <stdint.h>

#define NN 50000   // nodes
#define NE 800000  // edges
#define HD 128     // hidden
#define NL 4       // layers
#define NM 64      // nodes per block (node kernel)
#define EB 64      // edges per block (edge kernel)

typedef __bf16 bf16x8 __attribute__((ext_vector_type(8)));
typedef __bf16 bf16x4 __attribute__((ext_vector_type(4)));
typedef float  f32x4  __attribute__((ext_vector_type(4)));

__device__ __forceinline__ f32x4 mfma16(bf16x8 a, bf16x8 b, f32x4 c) {
  return __builtin_amdgcn_mfma_f32_16x16x32_bf16(a, b, c, 0, 0, 0);
}

template<int MT, int NT>
__device__ __forceinline__ void zero_acc(f32x4 (&acc)[MT][NT]) {
#pragma unroll
  for (int i = 0; i < MT; ++i)
#pragma unroll
    for (int j = 0; j < NT; ++j) acc[i][j] = f32x4{0.f, 0.f, 0.f, 0.f};
}

// ---------------- generic MT/NT gemm chunk ----------------------------------
template<int MT, int NT, int KS>
__device__ __forceinline__ void gemm_chunk(const __bf16* A, int sa,
    const __bf16* __restrict__ Bt, int Krow, int k0,
    int m_off, int n_off, int lane, f32x4 (&acc)[MT][NT])
{
  const int arow = lane & 15;
  const int quad = lane >> 4;
  bf16x8 b[KS][NT];
#pragma unroll
  for (int ks = 0; ks < KS; ++ks)
#pragma unroll
    for (int nt = 0; nt < NT; ++nt)
      b[ks][nt] = *reinterpret_cast<const bf16x8*>(
          Bt + (size_t)(n_off + nt * 16 + arow) * Krow + k0 + ks * 32 + quad * 8);
#pragma unroll
  for (int ks = 0; ks < KS; ++ks) {
    const int k = k0 + ks * 32 + quad * 8;
    bf16x8 a[MT];
#pragma unroll
    for (int mt = 0; mt < MT; ++mt)
      a[mt] = *reinterpret_cast<const bf16x8*>(A + (m_off + mt * 16 + arow) * sa + k);
#pragma unroll
    for (int mt = 0; mt < MT; ++mt)
#pragma unroll
      for (int nt = 0; nt < NT; ++nt)
        acc[mt][nt] = mfma16(a[mt], b[ks][nt], acc[mt][nt]);
  }
}

// C/D layout (m89-verified): col = lane&15, row = (lane>>4)*4 + reg
template<int MT, int NT, bool RELU>
__device__ __forceinline__ void store_tile(__bf16* O, int so,
    const float* __restrict__ bias, int m_off, int n_off, int lane,
    f32x4 (&acc)[MT][NT])
{
  const int quad = lane >> 4;
  const int cl = lane & 15;
#pragma unroll
  for (int nt = 0; nt < NT; ++nt) {
    const int col = n_off + nt * 16 + cl;
    const float bv = bias[col];
#pragma unroll
    for (int mt = 0; mt < MT; ++mt)
#pragma unroll
      for (int r = 0; r < 4; ++r) {
        const int row = m_off + mt * 16 + quad * 4 + r;
        float v = acc[mt][nt][r] + bv;
        if (RELU) v = fmaxf(v, 0.f);
        O[row * so + col] = (__bf16)v;
      }
  }
}

// ---- prep: W[l][K0][128] fp32 -> Wt[l][128][Kp] bf16 (transposed, zero-pad K)
__global__ void prep_w(const float* __restrict__ W, __bf16* __restrict__ Wt,
                       int K0, int Kp) {
  int idx = blockIdx.x * 256 + threadIdx.x;
  int total = NL * HD * Kp;
  if (idx >= total) return;
  int l = idx / (HD * Kp);
  int rem = idx - l * HD * Kp;
  int n = rem / Kp;
  int k = rem - n * Kp;
  float v = (k < K0) ? W[((size_t)l * K0 + k) * HD + n] : 0.f;
  Wt[idx] = (__bf16)v;
}

// ---- prep P/Q weights: fold rel_mom rows (260:263) into h_col/h_row blocks.
__global__ void prep_pqw(const float* __restrict__ We1,
                         __bf16* __restrict__ Wtopt, __bf16* __restrict__ Wbott) {
  int idx = blockIdx.x * 256 + threadIdx.x;
  if (idx >= NL * HD * HD) return;
  int l = idx / (HD * HD);
  int rem = idx - l * HD * HD;
  int n = rem >> 7;
  int k = rem & 127;
  const float* W = We1 + (size_t)l * 263 * HD;
  float extra = (k >= 3 && k < 6) ? W[(260 + k - 3) * HD + n] : 0.f;
  Wtopt[idx] = (__bf16)(W[k * HD + n] + extra);
  Wbott[idx] = (__bf16)(W[(128 + k) * HD + n] - extra);
}

// ---- h0 = x @ W_in + b_in
__global__ void h0_kernel(const float* __restrict__ x, const float* __restrict__ W,
                          const float* __restrict__ b, float* __restrict__ H32,
                          __bf16* __restrict__ HB) {
  int idx = blockIdx.x * 256 + threadIdx.x;
  if (idx >= NN * HD) return;
  int node = idx >> 7, j = idx & 127;
  const float* xr = x + node * 16;
  float s = b[j];
#pragma unroll
  for (int k = 0; k < 16; ++k) s += xr[k] * W[k * HD + j];
  H32[idx] = s;
  HB[idx] = (__bf16)s;
}

// ---- CSR build (counting sort of edges by col), emitting sorted ROW/COL
__global__ void hist_kernel(const int* __restrict__ ei, int* __restrict__ cnt) {
  int e = blockIdx.x * 256 + threadIdx.x;
  if (e < NE) atomicAdd(&cnt[ei[NE + e]], 1);
}

__global__ void scan_kernel(const int* __restrict__ cnt, int* __restrict__ cur) {
  __shared__ int wsum[16];
  __shared__ int carry;
  int t = threadIdx.x;           // 1024 threads
  int lane = t & 63, wid = t >> 6;
  if (t == 0) carry = 0;
  __syncthreads();
  for (int base = 0; base < NN; base += 1024) {
    int v = (base + t < NN) ? cnt[base + t] : 0;
    int incl = v;
#pragma unroll
    for (int off = 1; off < 64; off <<= 1) {
      int u = __shfl_up(incl, off, 64);
      if (lane >= off) incl += u;
    }
    if (lane == 63) wsum[wid] = incl;
    __syncthreads();
    int woff = 0;
    for (int k = 0; k < wid; ++k) woff += wsum[k];
    int c = carry;
    if (base + t < NN) cur[base + t] = c + woff + incl - v;
    __syncthreads();
    if (t == 1023) carry = c + woff + incl;
    __syncthreads();
  }
}

__global__ void scatter_kernel(const int* __restrict__ ei, int* __restrict__ cur,
                               int* __restrict__ ROWS, int* __restrict__ COLS) {
  int e = blockIdx.x * 256 + threadIdx.x;
  if (e < NE) {
    int r = ei[e], c = ei[NE + e];
    int p = atomicAdd(&cur[c], 1);
    ROWS[p] = r;
    COLS[p] = c;
  }
}

// ---- per-edge dist only (rel_pos part of ea is folded into P/Q)
__global__ void dist_kernel(const float* __restrict__ pos,
                            const int* __restrict__ ROWS, const int* __restrict__ COLS,
                            __bf16* __restrict__ DSTb) {
  int p = blockIdx.x * 256 + threadIdx.x;
  if (p >= NE) return;
  int r = ROWS[p], c = COLS[p];
  float dx = pos[c * 3 + 0] - pos[r * 3 + 0];
  float dy = pos[c * 3 + 1] - pos[r * 3 + 1];
  float dz = pos[c * 3 + 2] - pos[r * 3 + 2];
  DSTb[p] = (__bf16)sqrtf(dx * dx + dy * dy + dz * dz);
}

// ---- P/Q kernel v2: P = h@Wtop^T + pos@W4xyz + be1 ; Q = h@Wbot^T - pos@W4xyz
__global__ __launch_bounds__(256, 4) void pq_kernel(
    const __bf16* __restrict__ HB, const float* __restrict__ pos,
    const __bf16* __restrict__ Wtopt, const __bf16* __restrict__ Wbott,
    const float* __restrict__ W4xyz,   // We1_l rows 256..258 : [3][128]
    const float* __restrict__ be1,
    __bf16* __restrict__ PB, __bf16* __restrict__ QB)
{
  const int task = blockIdx.x * 4 + (threadIdx.x >> 6);
  const int lane = threadIdx.x & 63;
  const int g = task & 1;                 // 0 -> P, 1 -> Q
  const int base = (task >> 1) * 32;
  if (base >= NN) return;
  const int arow = lane & 15, quad = lane >> 4, cl = lane & 15;

  const __bf16* Wt = g ? Wbott : Wtopt;
  __bf16* O = g ? QB : PB;
  f32x4 acc[2][8];
  zero_acc(acc);
#pragma unroll
  for (int ks = 0; ks < 4; ++ks) {
    const int k = ks * 32 + quad * 8;
    bf16x8 b[8];
#pragma unroll
    for (int nt = 0; nt < 8; ++nt)
      b[nt] = *reinterpret_cast<const bf16x8*>(Wt + (size_t)(nt * 16 + arow) * HD + k);
    bf16x8 a[2];
#pragma unroll
    for (int mt = 0; mt < 2; ++mt) {
      int row = base + mt * 16 + arow;
      if (row >= NN) row = NN - 1;         // clamp (stores guarded)
      a[mt] = *reinterpret_cast<const bf16x8*>(HB + (size_t)row * HD + k);
    }
#pragma unroll
    for (int mt = 0; mt < 2; ++mt)
#pragma unroll
      for (int nt = 0; nt < 8; ++nt)
        acc[mt][nt] = mfma16(a[mt], b[nt], acc[mt][nt]);
  }
  float px[2][4], py[2][4], pz[2][4];
#pragma unroll
  for (int mt = 0; mt < 2; ++mt)
#pragma unroll
    for (int r = 0; r < 4; ++r) {
      int row = base + mt * 16 + quad * 4 + r;
      if (row >= NN) row = NN - 1;
      px[mt][r] = pos[row * 3 + 0];
      py[mt][r] = pos[row * 3 + 1];
      pz[mt][r] = pos[row * 3 + 2];
    }
#pragma unroll
  for (int nt = 0; nt < 8; ++nt) {
    const int col = nt * 16 + cl;
    const float w0 = W4xyz[col], w1 = W4xyz[HD + col], w2 = W4xyz[2 * HD + col];
    const float bb = g ? 0.f : be1[col];
#pragma unroll
    for (int mt = 0; mt < 2; ++mt)
#pragma unroll
      for (int r = 0; r < 4; ++r) {
        const int row = base + mt * 16 + quad * 4 + r;
        if (row < NN) {
          float dot = px[mt][r] * w0 + py[mt][r] * w1 + pz[mt][r] * w2;
          float v = acc[mt][nt][r] + (g ? -dot : dot) + bb;
          O[(size_t)row * HD + col] = (__bf16)v;
        }
      }
  }
}

// ---- edge kernel v4c: r7 structure; bounds (256,6) -> VGPR cap ~85 (no
// spills; r9's cap-64 spilled: WRITE 36->448MB), 6 blocks/CU = 75% occ.
__global__ __launch_bounds__(256, 6) void edge_kernel(
    const __bf16* __restrict__ PB, const __bf16* __restrict__ QB,
    const __bf16* __restrict__ DSTb,
    const int* __restrict__ ROWS, const int* __restrict__ COLS,
    const float* __restrict__ w4d,      // We1_l row 259 (dist), 128 f32
    const __bf16* __restrict__ We2t, const __bf16* __restrict__ We3t,
    const float* __restrict__ be2, const float* __restrict__ be3,
    float* __restrict__ AGG)
{
  __shared__ __bf16 S[EB * 136];
  __shared__ float w4ds[HD], be2s[HD], be3s[HD];
  __shared__ int colS[EB];
  const int t = threadIdx.x;
  const int base = blockIdx.x * EB;

  if (t < HD) { w4ds[t] = w4d[t]; be2s[t] = be2[t]; be3s[t] = be3[t]; }
  if (t < EB) colS[t] = COLS[base + t];
  __syncthreads();                              // B0: w4ds ready

  // ---- gather + combine -> m1 tile. thread t: row i = t>>2, 4 chunks of 8.
  {
    const int i = t >> 2, cg = t & 3;
    const int p = base + i;
    const int c = colS[i];
    const int r = ROWS[p];
    const float dist = (float)DSTb[p];
    const __bf16* Prow = PB + (size_t)c * HD;
    const __bf16* Qrow = QB + (size_t)r * HD;
#pragma unroll
    for (int u = 0; u < 4; ++u) {
      const int ch = cg * 4 + u;
      bf16x8 pv = *reinterpret_cast<const bf16x8*>(Prow + ch * 8);
      bf16x8 qv = *reinterpret_cast<const bf16x8*>(Qrow + ch * 8);
      bf16x8 o;
#pragma unroll
      for (int j = 0; j < 8; ++j) {
        const int col = ch * 8 + j;
        float f = (float)pv[j] + (float)qv[j] + dist * w4ds[col];
        o[j] = (__bf16)fmaxf(f, 0.f);
      }
      *reinterpret_cast<bf16x8*>(S + i * 136 + ch * 8) = o;
    }
  }
  __syncthreads();                              // B1: m1 complete

  const int w = t >> 6, lane = t & 63;
  const int m_off = (w >> 1) * 32, n_off = (w & 1) * 64;   // wave: 32x64 tile
  const int arow = lane & 15, quad = lane >> 4, cl = lane & 15;

  f32x4 acc[2][4];
#pragma unroll
  for (int g = 0; g < 2; ++g) {
    const __bf16* Wt = g ? We3t : We2t;
    const float* bs = g ? be3s : be2s;
    zero_acc(acc);
#pragma unroll
    for (int half = 0; half < 2; ++half) {      // K=128 as 2 batches of 64
      bf16x8 b[2][4];
#pragma unroll
      for (int ks = 0; ks < 2; ++ks)
#pragma unroll
        for (int nt = 0; nt < 4; ++nt)
          b[ks][nt] = *reinterpret_cast<const bf16x8*>(
              Wt + (size_t)(n_off + nt * 16 + arow) * HD + half * 64 + ks * 32 + quad * 8);
#pragma unroll
      for (int ks = 0; ks < 2; ++ks) {
        const int k = half * 64 + ks * 32 + quad * 8;
        bf16x8 a[2];
#pragma unroll
        for (int mt = 0; mt < 2; ++mt)
          a[mt] = *reinterpret_cast<const bf16x8*>(S + (m_off + mt * 16 + arow) * 136 + k);
#pragma unroll
        for (int mt = 0; mt < 2; ++mt)
#pragma unroll
          for (int nt = 0; nt < 4; ++nt)
            acc[mt][nt] = mfma16(a[mt], b[ks][nt], acc[mt][nt]);
      }
    }
    __syncthreads();                            // all waves done reading S
#pragma unroll
    for (int nt = 0; nt < 4; ++nt) {
      const int col = n_off + nt * 16 + cl;
      const float bv = bs[col];
#pragma unroll
      for (int mt = 0; mt < 2; ++mt)
#pragma unroll
        for (int r = 0; r < 4; ++r) {
          const int row = m_off + mt * 16 + quad * 4 + r;
          float v = acc[mt][nt][r] + bv;
          if (!g) v = fmaxf(v, 0.f);
          S[row * 136 + col] = (__bf16)v;
        }
    }
    __syncthreads();                            // m(g+2) visible to all
  }

  // ---- block-level segmented reduce (r3-proven): col j, 32-row halves.
  {
    const int j = t & 127, hh = t >> 7;
    const int i0 = hh * 32, i1 = i0 + 32;
    float s = 0.f;
    for (int i = i0; i < i1; ++i) {
      s += (float)S[i * 136 + j];
      const int c = colS[i];
      if (i == i1 - 1 || colS[i + 1] != c) {
        atomicAdd(&AGG[(size_t)c * HD + j], s);
        s = 0.f;
      }
    }
  }
}

// ---- node MLP + residual + LayerNorm. 64 nodes/block, MT=2/NT=4 waves,
// LDS ~36.5 KB -> 4 blocks/CU (r9-verified: ~65 us/dispatch).
__global__ __launch_bounds__(256, 4) void node_kernel(
    const __bf16* __restrict__ HBin, const float* __restrict__ AGG,
    const __bf16* __restrict__ Wn1t, const __bf16* __restrict__ Wn2t,
    const __bf16* __restrict__ Wn3t,
    const float* __restrict__ bn1, const float* __restrict__ bn2,
    const float* __restrict__ bn3,
    const float* __restrict__ lng, const float* __restrict__ lnb,
    float* __restrict__ H32, __bf16* __restrict__ HBout,
    float* __restrict__ dout)
{
  __shared__ float SB[NM * 136];                 // 34.8 KB union
  __shared__ float ps[NM][2], psq[NM][2];
  __shared__ float mean_s[NM], rstd_s[NM];
  __bf16* B16 = reinterpret_cast<__bf16*>(SB);
  const int t = threadIdx.x;
  const int base = blockIdx.x * NM;

  {
    const int i0 = t >> 4, s = t & 15;
#pragma unroll
    for (int g = 0; g < NM / 16; ++g) {
      const int i = g * 16 + i0;
      const int node = base + i;
      uint4 v = make_uint4(0, 0, 0, 0);
      if (node < NN) v = *(reinterpret_cast<const uint4*>(HBin + (size_t)node * HD) + s);
      *reinterpret_cast<uint4*>(&B16[i * 264 + s * 8]) = v;
    }
  }
  for (int idx = t; idx < NM * 32; idx += 256) {
    const int i = idx >> 5, c4 = idx & 31;
    const int node = base + i;
    float4 v = make_float4(0.f, 0.f, 0.f, 0.f);
    if (node < NN) v = *reinterpret_cast<const float4*>(AGG + (size_t)node * HD + c4 * 4);
    __bf16* d = &B16[i * 264 + HD + c4 * 4];
    d[0] = (__bf16)v.x; d[1] = (__bf16)v.y; d[2] = (__bf16)v.z; d[3] = (__bf16)v.w;
  }
  __syncthreads();

  const int w = t >> 6, lane = t & 63;
  const int m_off = (w >> 1) * 32, n_off = (w & 1) * 64;   // wave: 32x64 tile
  f32x4 acc[2][4];
  __bf16* reg0 = B16;                            // stride 136, [0, 17408)
  __bf16* reg1 = B16 + NM * 136;                 // stride 136, [17408, 34816)

  zero_acc(acc);
  gemm_chunk<2, 4, 4>(B16, 264, Wn1t, 256, 0,   m_off, n_off, lane, acc);
  gemm_chunk<2, 4, 4>(B16, 264, Wn1t, 256, 128, m_off, n_off, lane, acc);
  __syncthreads();                               // A reads done
  store_tile<2, 4, true>(reg0, 136, bn1, m_off, n_off, lane, acc);
  __syncthreads();
  zero_acc(acc);
  gemm_chunk<2, 4, 4>(reg0, 136, Wn2t, 128, 0, m_off, n_off, lane, acc);
  store_tile<2, 4, true>(reg1, 136, bn2, m_off, n_off, lane, acc);   // disjoint
  __syncthreads();
  zero_acc(acc);
  gemm_chunk<2, 4, 4>(reg1, 136, Wn3t, 128, 0, m_off, n_off, lane, acc);
  __syncthreads();                               // reg1 reads done

  {
    const int quad = lane >> 4, cl = lane & 15;
#pragma unroll
    for (int nt = 0; nt < 4; ++nt) {
      const int col = n_off + nt * 16 + cl;
      const float bv = bn3[col];
#pragma unroll
      for (int mt = 0; mt < 2; ++mt)
#pragma unroll
        for (int r = 0; r < 4; ++r) {
          const int row = m_off + mt * 16 + quad * 4 + r;
          const int node = base + row;
          float hv = (node < NN) ? H32[(size_t)node * HD + col] : 0.f;
          SB[row * 136 + col] = hv + acc[mt][nt][r] + bv;
        }
    }
  }
  __syncthreads();
  if (t < 128) {
    const int r = t >> 1, hh = t & 1;
    float s = 0.f, sq = 0.f;
    for (int j = hh * 64; j < hh * 64 + 64; ++j) {
      float v = SB[r * 136 + j];
      s += v; sq += v * v;
    }
    ps[r][hh] = s; psq[r][hh] = sq;
  }
  __syncthreads();
  if (t < NM) {
    float s = ps[t][0] + ps[t][1];
    float sq = psq[t][0] + psq[t][1];
    float mean = s * (1.f / HD);
    float var = sq * (1.f / HD) - mean * mean;
    mean_s[t] = mean;
    rstd_s[t] = rsqrtf(var + 1e-5f);
  }
  __syncthreads();
  for (int idx = t; idx < NM * HD; idx += 256) {
    const int r = idx >> 7, j = idx & 127;
    const int node = base + r;
    if (node < NN) {
      float v = (SB[r * 136 + j] - mean_s[r]) * rstd_s[r] * lng[j] + lnb[j];
      H32[(size_t)node * HD + j] = v;
      HBout[(size_t)node * HD + j] = (__bf16)v;
      if (dout) dout[(size_t)node * HD + j] = v;
    }
  }
}

extern "C" void kernel_launch(void* const* d_in, const int* in_sizes, int n_in,
                              void* d_out, int out_size, void* d_ws, size_t ws_size,
                              hipStream_t stream)
{
  const float* x    = (const float*)d_in[0];
  const float* pos  = (const float*)d_in[1];
  const int*   ei   = (const int*)d_in[2];
  const float* W_in = (const float*)d_in[3];
  const float* b_in = (const float*)d_in[4];
  const float* We1  = (const float*)d_in[5];
  const float* be1  = (const float*)d_in[6];
  const float* We2  = (const float*)d_in[7];
  const float* be2  = (const float*)d_in[8];
  const float* We3  = (const float*)d_in[9];
  const float* be3  = (const float*)d_in[10];
  const float* Wn1  = (const float*)d_in[11];
  const float* bn1  = (const float*)d_in[12];
  const float* Wn2  = (const float*)d_in[13];
  const float* bn2  = (const float*)d_in[14];
  const float* Wn3  = (const float*)d_in[15];
  const float* bn3  = (const float*)d_in[16];
  const float* lng  = (const float*)d_in[17];
  const float* lnb  = (const float*)d_in[18];
  float* out = (float*)d_out;

  char* ws = (char*)d_ws;
  size_t off = 0;
  auto alloc = [&](size_t bytes) -> char* {
    char* p = ws + off;
    off += (bytes + 255) & ~(size_t)255;
    return p;
  };
  __bf16* Wtopt = (__bf16*)alloc((size_t)NL * HD * HD * 2);
  __bf16* Wbott = (__bf16*)alloc((size_t)NL * HD * HD * 2);
  __bf16* We2t = (__bf16*)alloc((size_t)NL * HD * HD * 2);
  __bf16* We3t = (__bf16*)alloc((size_t)NL * HD * HD * 2);
  __bf16* Wn1t = (__bf16*)alloc((size_t)NL * HD * 256 * 2);
  __bf16* Wn2t = (__bf16*)alloc((size_t)NL * HD * HD * 2);
  __bf16* Wn3t = (__bf16*)alloc((size_t)NL * HD * HD * 2);
  __bf16* DSTb = (__bf16*)alloc((size_t)NE * 2);
  float*  H32  = (float*) alloc((size_t)NN * HD * 4);
  __bf16* HB   = (__bf16*)alloc((size_t)NN * HD * 2);
  __bf16* PB   = (__bf16*)alloc((size_t)NN * HD * 2);
  __bf16* QB   = (__bf16*)alloc((size_t)NN * HD * 2);
  float*  AGG  = (float*) alloc((size_t)NN * HD * 4);
  int*    CNT  = (int*)   alloc((size_t)NN * 4);
  int*    CUR  = (int*)   alloc((size_t)NN * 4);
  int*    ROWS = (int*)   alloc((size_t)NE * 4);
  int*    COLS = (int*)   alloc((size_t)NE * 4);

  hipMemsetAsync(CNT, 0, (size_t)NN * 4, stream);
  prep_pqw<<<(NL * HD * HD + 255) / 256, 256, 0, stream>>>(We1, Wtopt, Wbott);
  prep_w<<<(NL * HD * HD + 255) / 256, 256, 0, stream>>>(We2, We2t, 128, 128);
  prep_w<<<(NL * HD * HD + 255) / 256, 256, 0, stream>>>(We3, We3t, 128, 128);
  prep_w<<<(NL * HD * 256 + 255) / 256, 256, 0, stream>>>(Wn1, Wn1t, 256, 256);
  prep_w<<<(NL * HD * HD + 255) / 256, 256, 0, stream>>>(Wn2, Wn2t, 128, 128);
  prep_w<<<(NL * HD * HD + 255) / 256, 256, 0, stream>>>(Wn3, Wn3t, 128, 128);
  h0_kernel<<<(NN * HD + 255) / 256, 256, 0, stream>>>(x, W_in, b_in, H32, HB);
  hist_kernel<<<(NE + 255) / 256, 256, 0, stream>>>(ei, CNT);
  scan_kernel<<<1, 1024, 0, stream>>>(CNT, CUR);
  scatter_kernel<<<(NE + 255) / 256, 256, 0, stream>>>(ei, CUR, ROWS, COLS);
  dist_kernel<<<(NE + 255) / 256, 256, 0, stream>>>(pos, ROWS, COLS, DSTb);

  const int pq_tasks = 2 * ((NN + 31) / 32);
  const int pq_blocks = (pq_tasks + 3) / 4;
  for (int l = 0; l < NL; ++l) {
    const float* We1l = We1 + (size_t)l * 263 * HD;
    pq_kernel<<<pq_blocks, 256, 0, stream>>>(HB, pos,
        Wtopt + (size_t)l * HD * HD, Wbott + (size_t)l * HD * HD,
        We1l + 256 * HD,            // W4xyz rows 256..258
        be1 + l * HD, PB, QB);
    hipMemsetAsync(AGG, 0, (size_t)NN * HD * 4, stream);
    edge_kernel<<<NE / EB, 256, 0, stream>>>(PB, QB, DSTb, ROWS, COLS,
        We1l + 259 * HD,            // w4d (dist row)
        We2t + (size_t)l * HD * HD, We3t + (size_t)l * HD * HD,
        be2 + l * HD, be3 + l * HD, AGG);
    node_kernel<<<(NN + NM - 1) / NM, 256, 0, stream>>>(HB, AGG,
        Wn1t + (size_t)l * HD * 256, Wn2t + (size_t)l * HD * HD,
        Wn3t + (size_t)l * HD * HD,
        bn1 + l * HD, bn2 + l * HD, bn3 + l * HD,
        lng + l * HD, lnb + l * HD,
        H32, HB, (l == NL - 1) ? out : nullptr);
  }
}